// Round 8
// baseline (798.271 us; speedup 1.0000x reference)
//
#include <hip/hip_runtime.h>
#include <hip/hip_cooperative_groups.h>

// ToDenseBEVConvolution R8 — single cooperative kernel, 5 phases:
//  ph0 init:  head=-1, bm=0 (grid-stride; replaces host memsets)
//  ph1 point: wave per point (grid-stride); [1,64]x[64,128] matmul with K read
//             directly from L2 (512KB, resident); writes f[N,128]; builds
//             head/nxt lists (spread atomicExch) + bm bitmask (spread atomicOr)
//  ph2 scan:  block 0: wordbase[w] = exclusive prefix of popc(bm[w]), uint4 loads
//  ph3 accum: wave per point; owner (head[cell]==pt) sums collision list,
//             writes compacted g[rank][128] (coalesced 512B)
//  ph4 dense: grid-stride float4 over out; rank via wordbase+popc; nt-store.
// Rationale (R7 post-mortem): three designs all landed ours~180us because
// ~10us/dispatch-boundary x 7-9 dispatches dominates. One dispatch kills that.
// Fallback: if cooperative launch fails, run the same kernel 5x (phase=0..4).

#define CIN    64
#define COUT   128
#define HW     (512 * 512)       // 2^18

typedef float nvec4 __attribute__((ext_vector_type(4)));
namespace cg = cooperative_groups;

__global__ __launch_bounds__(256, 2) void bev_fused(
    const int*    __restrict__ coords,    // [N,4] (x,h,z,b)
    const float*  __restrict__ feats,     // [N,64]
    const float*  __restrict__ kern,      // [16,64,128]
    const int*    __restrict__ stride_p,  // [1]
    float*        __restrict__ f,         // [N,128] ws
    int*          __restrict__ head,      // [ncells] ws
    int*          __restrict__ nxt,       // [N] ws
    unsigned int* __restrict__ bm,        // [ncells/32] ws
    int*          __restrict__ wordbase,  // [ncells/32] ws
    float*        __restrict__ g,         // [N,128] ws (compacted rows)
    float*        __restrict__ out,       // [B,128,512,512]
    int n, int ncells, int total4, int phase)    // phase<0 => cooperative all-phase
{
    const int gsz    = gridDim.x * blockDim.x;
    const int gtid   = blockIdx.x * blockDim.x + threadIdx.x;
    const int nwords = ncells >> 5;
    const bool coop  = (phase < 0);

    // ---------------- phase 0: init ----------------
    if (coop || phase == 0) {
        for (int i = gtid; i < ncells; i += gsz) head[i] = -1;
        for (int i = gtid; i < nwords; i += gsz) bm[i] = 0;
    }
    if (coop) { __threadfence(); cg::this_grid().sync(); }

    // ---------------- phase 1: per-point matmul + lists ----------------
    if (coop || phase == 1) {
        const int lane   = threadIdx.x & 63;
        const int nwaves = gsz >> 6;
        const int stride = stride_p[0];
        for (int pp = gtid >> 6; pp < n; pp += nwaves) {
            const int pt = __builtin_amdgcn_readfirstlane(pp);  // wave-uniform
            const int cx = coords[pt * 4 + 0];
            const int ch = coords[pt * 4 + 1];
            const int cz = coords[pt * 4 + 2];
            const int cb = coords[pt * 4 + 3];
            const int k  = ch / stride;
            const float* fp = feats + (size_t)pt * CIN;
            const float* kp = kern + (size_t)k * (CIN * COUT) + 2 * lane;
            float ax = 0.f, ay = 0.f;
#pragma unroll
            for (int c = 0; c < CIN; ++c) {
                const float fv = fp[c];                            // s_load (uniform)
                const float2 kv = *(const float2*)(kp + c * COUT); // 512B/wave, L2-hit
                ax = fmaf(fv, kv.x, ax);
                ay = fmaf(fv, kv.y, ay);
            }
            *(float2*)(f + (size_t)pt * COUT + 2 * lane) = make_float2(ax, ay);
            if (lane == 0) {
                const int cell = (cb << 18) + ((cx / stride) << 9) + (cz / stride);
                const int old = atomicExch(&head[cell], pt);   // spread: cheap
                nxt[pt] = old;
                atomicOr(&bm[cell >> 5], 1u << (cell & 31));   // spread: cheap
            }
        }
    }
    if (coop) { __threadfence(); cg::this_grid().sync(); }

    // ---------------- phase 2: popc prefix scan (block 0) ----------------
    if ((coop || phase == 2) && blockIdx.x == 0) {
        __shared__ int part[256];
        const int tid = threadIdx.x;
        const int per = (nwords + 255) / 256;
        const int w0  = tid * per;
        int s = 0;
        for (int i = 0; i + 3 < per; i += 4) {               // vectorized popc sweep
            if (w0 + i + 3 < nwords) {
                const uint4 w = *(const uint4*)(bm + w0 + i);
                s += __popc(w.x) + __popc(w.y) + __popc(w.z) + __popc(w.w);
            } else {
                for (int j = i; j < per; ++j)
                    if (w0 + j < nwords) s += __popc(bm[w0 + j]);
                break;
            }
        }
        part[tid] = s;
        __syncthreads();
        for (int d = 1; d < 256; d <<= 1) {                  // Hillis-Steele
            const int v = (tid >= d) ? part[tid - d] : 0;
            __syncthreads();
            part[tid] += v;
            __syncthreads();
        }
        int base = (tid == 0) ? 0 : part[tid - 1];           // exclusive
        for (int i = 0; i < per; ++i) {
            const int w = w0 + i;
            if (w < nwords) { wordbase[w] = base; base += __popc(bm[w]); }
        }
    }
    if (coop) { __threadfence(); cg::this_grid().sync(); }

    // ---------------- phase 3: owner accumulates -> compacted g ----------------
    if (coop || phase == 3) {
        const int lane   = threadIdx.x & 63;
        const int nwaves = gsz >> 6;
        const int stride = stride_p[0];
        for (int pp = gtid >> 6; pp < n; pp += nwaves) {
            const int pt = __builtin_amdgcn_readfirstlane(pp);
            const int cx = coords[pt * 4 + 0];
            const int cz = coords[pt * 4 + 2];
            const int cb = coords[pt * 4 + 3];
            const int cell = (cb << 18) + ((cx / stride) << 9) + (cz / stride);
            if (__builtin_amdgcn_readfirstlane(head[cell]) != pt) continue; // owner only
            float sx = 0.f, sy = 0.f;
            int p = pt;
            while (p >= 0) {                                 // avg list len ~1.04
                const float2 v = *(const float2*)(f + (size_t)p * COUT + 2 * lane);
                sx += v.x; sy += v.y;
                p = __builtin_amdgcn_readfirstlane(nxt[p]);
            }
            const unsigned int word = bm[cell >> 5];
            const int bit  = cell & 31;
            const int rank = wordbase[cell >> 5] + __popc(word & ((1u << bit) - 1u));
            *(float2*)(g + (size_t)rank * COUT + 2 * lane) = make_float2(sx, sy);
        }
    }
    if (coop) { __threadfence(); cg::this_grid().sync(); }

    // ---------------- phase 4: fused zero+gather dense output ----------------
    if (coop || phase == 4) {
        for (int t = gtid; t < total4; t += gsz) {
            const int linear = t << 2;                       // z%4==0
            const int z = linear & 511;
            const int x = (linear >> 9) & 511;
            const int o = (linear >> 18) & 127;
            const int b = linear >> 25;
            const int cell = (b << 18) + (x << 9) + z;
            const unsigned int word = bm[cell >> 5];
            const int bit = cell & 31;
            const unsigned int nib = (word >> bit) & 0xFu;
            nvec4 v = {0.f, 0.f, 0.f, 0.f};
            if (nib) {
                int r = wordbase[cell >> 5] + __popc(word & ((1u << bit) - 1u));
#pragma unroll
                for (int j = 0; j < 4; ++j)
                    if (nib & (1u << j)) { v[j] = g[(size_t)r * COUT + o]; ++r; }
            }
            __builtin_nontemporal_store(v, (nvec4*)(out + linear));
        }
    }
}

// ------------------------------------------------------------------- launch
extern "C" void kernel_launch(void* const* d_in, const int* in_sizes, int n_in,
                              void* d_out, int out_size, void* d_ws, size_t ws_size,
                              hipStream_t stream) {
    const int*   coords   = (const int*)d_in[0];
    const float* feats    = (const float*)d_in[1];
    const float* kern     = (const float*)d_in[2];
    const int*   stride_p = (const int*)d_in[3];
    float* out = (float*)d_out;

    int n      = in_sizes[0] / 4;        // coords is [N,4]
    int ncells = out_size / COUT;        // B*H*W
    int nwords = ncells / 32;
    int total4 = out_size / 4;

    // Workspace: f | g | head | nxt | wordbase | bm   (all re-inited in-kernel)
    size_t off = 0;
    float* f = (float*)((char*)d_ws + off);            off += (size_t)n * COUT * sizeof(float);
    float* g = (float*)((char*)d_ws + off);            off += (size_t)n * COUT * sizeof(float);
    int* head = (int*)((char*)d_ws + off);             off += (size_t)ncells * sizeof(int);
    int* nxt  = (int*)((char*)d_ws + off);             off += (size_t)n * sizeof(int);
    int* wordbase = (int*)((char*)d_ws + off);         off += (size_t)nwords * sizeof(int);
    unsigned int* bm = (unsigned int*)((char*)d_ws + off); off += (size_t)nwords * sizeof(unsigned int);

    int phase = -1;
    void* args[] = {
        (void*)&coords, (void*)&feats, (void*)&kern, (void*)&stride_p,
        (void*)&f, (void*)&head, (void*)&nxt, (void*)&bm, (void*)&wordbase,
        (void*)&g, (void*)&out, (void*)&n, (void*)&ncells, (void*)&total4,
        (void*)&phase
    };

    // 512 blocks = 2 blocks/CU guaranteed co-resident (launch_bounds(256,2),
    // 1KB LDS, VGPR<=256). Grid-stride loops inside handle all sizes.
    hipError_t e = hipLaunchCooperativeKernel((const void*)bev_fused,
                                              dim3(512), dim3(256), args, 0, stream);
    if (e != hipSuccess) {
        // Deterministic fallback: same kernel, 5 sequential phase launches.
        for (int ph = 0; ph <= 4; ++ph) {
            const int blocks = (ph == 4) ? 8192 : 1024;
            bev_fused<<<blocks, 256, 0, stream>>>(coords, feats, kern, stride_p,
                                                  f, head, nxt, bm, wordbase, g,
                                                  out, n, ncells, total4, ph);
        }
    }
}

// Round 9
// 391.280 us; speedup vs baseline: 2.0402x; 2.0402x over previous
//
#include <hip/hip_runtime.h>

// ToDenseBEVConvolution R9 — R7 structure, dense pass rewritten:
//  K1 bev_sort:  bucket point indices by k-bin (unchanged).
//  K2 bev_point: binned matmul, kern[k] in LDS, f[N,128] + head/nxt + bm (unchanged).
//  K3 bev_scan:  popc prefix over bm words (unchanged).
//  K4 bev_accum: owner sums collision list -> compacted g[rank][128] (unchanged).
//  K5 bev_dense_row (NEW): one WAVE per 2KB output row (b,o,x). Plain (not nt)
//     float4 stores, two coalesced 1KB store insts/wave; bm+wordbase loads = one
//     line/wave; o,b wave-uniform (scalar); a row's occupied ranks are
//     consecutive -> g gathers land in a contiguous ~19KB window reused by all
//     128 o-waves of the same (b,x) (L2-hot).
//  R8 lesson: cooperative 512-block fusion starves TLP (570us measured) — keep
//  separate full-size dispatches. This round isolates the dense-writer change.

#define CIN    64
#define COUT   128
#define BEVH   512
#define BEVW   512
#define HW     (BEVH * BEVW)     // 2^18
#define NBINS  16
#define PTS_PER_WAVE  8
#define PTS_PER_BLOCK 32

// ---------------------------------------------------------------- K1: bucket
__global__ __launch_bounds__(256) void bev_sort(
    const int* __restrict__ coords,   // [N,4]
    const int* __restrict__ stride_p,
    int*       __restrict__ gcnt,     // [16] init 0
    int*       __restrict__ sorted,   // [16*N]
    int n)
{
    __shared__ int hist[NBINS];
    __shared__ int base[NBINS];
    const int tid = threadIdx.x;
    if (tid < NBINS) hist[tid] = 0;
    __syncthreads();

    const int i = blockIdx.x * 256 + tid;
    int k = 0, rank = 0;
    if (i < n) {
        k = coords[i * 4 + 1] / stride_p[0];
        rank = atomicAdd(&hist[k], 1);        // LDS atomic: block-local rank
    }
    __syncthreads();
    if (tid < NBINS)
        base[tid] = hist[tid] ? atomicAdd(&gcnt[tid], hist[tid]) : 0;
    __syncthreads();
    if (i < n)
        sorted[k * n + base[k] + rank] = i;
}

// ------------------------------------------------------- K2: per-point matmul
__global__ __launch_bounds__(256) void bev_point(
    const int*   __restrict__ coords,
    const float* __restrict__ feats,    // [N,64]
    const float* __restrict__ kern,     // [16,64,128]
    const int*   __restrict__ stride_p,
    const int*   __restrict__ gcnt,     // [16]
    const int*   __restrict__ sorted,   // [16*N]
    float*       __restrict__ f,        // [N,128]
    int*         __restrict__ head,     // [ncells] init -1
    int*         __restrict__ nxt,      // [N]
    unsigned int* __restrict__ bm,      // [ncells/32] init 0
    int n, int chunks_per_bin)
{
    __shared__ float lk[CIN * COUT];    // 32 KB: kern[bin]

    const int bin   = blockIdx.x / chunks_per_bin;
    const int chunk = blockIdx.x % chunks_per_bin;
    const int cnt   = gcnt[bin];
    const int r0blk = chunk * PTS_PER_BLOCK;
    if (r0blk >= cnt) return;                 // uniform across block, pre-barrier: ok

    // stage kern[bin] -> LDS (256 thr x 8 float4)
    {
        const float4* src = (const float4*)(kern + (size_t)bin * CIN * COUT);
        float4* dst = (float4*)lk;
#pragma unroll
        for (int j = 0; j < 8; ++j)
            dst[j * 256 + threadIdx.x] = src[j * 256 + threadIdx.x];
    }
    __syncthreads();

    const int wave = threadIdx.x >> 6;
    const int lane = threadIdx.x & 63;
    const int r0 = r0blk + wave * PTS_PER_WAVE;
    const int navail = cnt - r0;
    if (navail <= 0) return;                  // no barrier after this point
    const int np = navail < PTS_PER_WAVE ? navail : PTS_PER_WAVE;

    int pts[PTS_PER_WAVE];
#pragma unroll
    for (int p = 0; p < PTS_PER_WAVE; ++p) {
        const int rr = (p < np) ? (r0 + p) : r0;   // pad tail with p0 (discarded)
        pts[p] = __builtin_amdgcn_readfirstlane(sorted[bin * n + rr]);
    }

    float ax[PTS_PER_WAVE], ay[PTS_PER_WAVE];
#pragma unroll
    for (int p = 0; p < PTS_PER_WAVE; ++p) { ax[p] = 0.f; ay[p] = 0.f; }

#pragma unroll
    for (int c = 0; c < CIN; ++c) {
        const float2 kv = *(const float2*)&lk[c * COUT + 2 * lane];
#pragma unroll
        for (int p = 0; p < PTS_PER_WAVE; ++p) {
            const float fv = feats[(size_t)pts[p] * CIN + c];  // wave-uniform -> s_load
            ax[p] = fmaf(fv, kv.x, ax[p]);
            ay[p] = fmaf(fv, kv.y, ay[p]);
        }
    }

#pragma unroll
    for (int p = 0; p < PTS_PER_WAVE; ++p) {
        if (p < np)
            *(float2*)(f + (size_t)pts[p] * COUT + 2 * lane) = make_float2(ax[p], ay[p]);
    }

    if (lane == 0) {
        const int stride = stride_p[0];
        for (int p = 0; p < np; ++p) {
            const int pt = pts[p];
            const int cx = coords[pt * 4 + 0];
            const int cz = coords[pt * 4 + 2];
            const int cb = coords[pt * 4 + 3];
            const int cell = (cb << 18) + ((cx / stride) << 9) + (cz / stride);
            const int old = atomicExch(&head[cell], pt);       // spread: cheap
            nxt[pt] = old;
            atomicOr(&bm[cell >> 5], 1u << (cell & 31));       // spread: cheap
        }
    }
}

// --------------------------------------- K3: word-level popcount prefix scan
__global__ __launch_bounds__(256) void bev_scan(
    const unsigned int* __restrict__ bm,        // [nwords]
    int*                __restrict__ wordbase,  // [nwords] exclusive prefix
    int nwords)
{
    __shared__ int part[256];
    const int tid = threadIdx.x;
    const int per = (nwords + 255) / 256;       // 64 for B=2
    const int w0  = tid * per;

    int s = 0;
    for (int i = 0; i < per; ++i) {
        const int w = w0 + i;
        if (w < nwords) s += __popc(bm[w]);
    }
    part[tid] = s;
    __syncthreads();
    for (int d = 1; d < 256; d <<= 1) {         // Hillis-Steele inclusive scan
        const int v = (tid >= d) ? part[tid - d] : 0;
        __syncthreads();
        part[tid] += v;
        __syncthreads();
    }
    int base = (tid == 0) ? 0 : part[tid - 1];  // exclusive
    for (int i = 0; i < per; ++i) {
        const int w = w0 + i;
        if (w < nwords) { wordbase[w] = base; base += __popc(bm[w]); }
    }
}

// ----------------------------- K4: owner combines collisions -> compacted g
__global__ __launch_bounds__(256) void bev_accum(
    const int*          __restrict__ coords,
    const int*          __restrict__ stride_p,
    const float*        __restrict__ f,         // [N,128]
    const int*          __restrict__ head,
    const int*          __restrict__ nxt,
    const unsigned int* __restrict__ bm,
    const int*          __restrict__ wordbase,
    float*              __restrict__ g,         // [nocc,128] compacted
    int n)
{
    const int wave = threadIdx.x >> 6;
    const int lane = threadIdx.x & 63;
    int pt = blockIdx.x * 4 + wave;
    if (pt >= n) return;
    pt = __builtin_amdgcn_readfirstlane(pt);

    const int stride = stride_p[0];
    const int cx = coords[pt * 4 + 0];
    const int cz = coords[pt * 4 + 2];
    const int cb = coords[pt * 4 + 3];
    const int cell = (cb << 18) + ((cx / stride) << 9) + (cz / stride);

    // exactly one point per occupied cell is the list head: that wave owns it
    if (__builtin_amdgcn_readfirstlane(head[cell]) != pt) return;

    float sx = 0.f, sy = 0.f;
    int p = pt;
    while (p >= 0) {                            // wave-uniform walk, avg len ~1.04
        const float2 v = *(const float2*)(f + (size_t)p * COUT + 2 * lane);
        sx += v.x; sy += v.y;
        p = __builtin_amdgcn_readfirstlane(nxt[p]);
    }

    const unsigned int word = bm[cell >> 5];
    const int bit = cell & 31;
    const int rank = wordbase[cell >> 5] + __popc(word & ((1u << bit) - 1u));

    *(float2*)(g + (size_t)rank * COUT + 2 * lane) = make_float2(sx, sy);  // 512B/cell
}

// ------------------------- K5: wave-per-row dense output (plain stores)
__global__ __launch_bounds__(256) void bev_dense_row(
    const float*        __restrict__ g,         // [nocc,128]
    const unsigned int* __restrict__ bm,
    const int*          __restrict__ wordbase,
    float*              __restrict__ out,       // [B,128,512,512]
    int nrows)                                  // B*COUT*BEVH
{
    const int wave = threadIdx.x >> 6;
    const int lane = threadIdx.x & 63;
    const int row = blockIdx.x * 4 + wave;      // row = ((b*128+o)*512)+x
    if (row >= nrows) return;

    const int x = row & 511;
    const int o = (row >> 9) & 127;             // wave-uniform
    const int b = row >> 16;                    // wave-uniform
    const int wbase = ((b << 18) + (x << 9)) >> 5;   // 16 bm words, one 64B line
    float* const orow = out + (size_t)row * 512;

#pragma unroll
    for (int h = 0; h < 2; ++h) {
        const int z    = h * 256 + lane * 4;    // lane covers 4 consecutive z
        const int widx = wbase + (z >> 5);      // 8 consecutive words per half
        const unsigned int word = bm[widx];
        const int bit = z & 31;
        const unsigned int nib = (word >> bit) & 0xFu;

        float4 v = make_float4(0.f, 0.f, 0.f, 0.f);
        if (nib) {                              // row's ranks are consecutive ->
            int r = wordbase[widx] + __popc(word & ((1u << bit) - 1u));
            float vv[4];
#pragma unroll
            for (int j = 0; j < 4; ++j) {       // contiguous g window, L2-hot
                vv[j] = 0.f;
                if (nib & (1u << j)) { vv[j] = g[(size_t)r * COUT + o]; ++r; }
            }
            v = make_float4(vv[0], vv[1], vv[2], vv[3]);
        }
        *(float4*)(orow + z) = v;               // coalesced 1KB/wave plain store
    }
}

// ------------------------------------------------------------------- launch
extern "C" void kernel_launch(void* const* d_in, const int* in_sizes, int n_in,
                              void* d_out, int out_size, void* d_ws, size_t ws_size,
                              hipStream_t stream) {
    const int*   coords   = (const int*)d_in[0];
    const float* feats    = (const float*)d_in[1];
    const float* kern     = (const float*)d_in[2];
    const int*   stride_p = (const int*)d_in[3];
    float* out = (float*)d_out;

    const int n      = in_sizes[0] / 4;      // coords is [N,4]
    const int ncells = out_size / COUT;      // B*H*W = 524288
    const int nwords = ncells / 32;          // 16384

    // Workspace: f | g | sorted | head | nxt | wordbase | bm | gcnt
    size_t off = 0;
    float* f = (float*)((char*)d_ws + off);          off += (size_t)n * COUT * sizeof(float);
    float* g = (float*)((char*)d_ws + off);          off += (size_t)n * COUT * sizeof(float);
    int* sorted = (int*)((char*)d_ws + off);         off += (size_t)NBINS * n * sizeof(int);
    int* head = (int*)((char*)d_ws + off);           off += (size_t)ncells * sizeof(int);
    int* nxt  = (int*)((char*)d_ws + off);           off += (size_t)n * sizeof(int);
    int* wordbase = (int*)((char*)d_ws + off);       off += (size_t)nwords * sizeof(int);
    unsigned int* bm = (unsigned int*)((char*)d_ws + off); off += (size_t)nwords * sizeof(unsigned int);
    int* gcnt = (int*)((char*)d_ws + off);           off += NBINS * sizeof(int);

    // ws re-poisoned to 0xAA before every timed launch -> re-init.
    (void)hipMemsetAsync(head, 0xFF, (size_t)ncells * sizeof(int), stream);     // -1
    (void)hipMemsetAsync(bm, 0,
                         (size_t)nwords * sizeof(unsigned int) + NBINS * sizeof(int),
                         stream);                                               // bm + gcnt

    bev_sort<<<(n + 255) / 256, 256, 0, stream>>>(coords, stride_p, gcnt, sorted, n);

    const int chunks_per_bin = (n + PTS_PER_BLOCK - 1) / PTS_PER_BLOCK;
    bev_point<<<NBINS * chunks_per_bin, 256, 0, stream>>>(
        coords, feats, kern, stride_p, gcnt, sorted, f, head, nxt, bm,
        n, chunks_per_bin);

    bev_scan<<<1, 256, 0, stream>>>(bm, wordbase, nwords);

    bev_accum<<<(n + 3) / 4, 256, 0, stream>>>(coords, stride_p, f, head, nxt,
                                               bm, wordbase, g, n);

    const int nrows = out_size / 512;        // B*COUT*BEVH = 131072
    bev_dense_row<<<nrows / 4, 256, 0, stream>>>(g, bm, wordbase, out, nrows);
}